// Round 9
// baseline (129.196 us; speedup 1.0000x reference)
//
#include <hip/hip_runtime.h>
#include <cmath>

constexpr int NOBJ = 256, CNUM = 151, DDIM = 512;
constexpr int NBDD = NOBJ * DDIM;  // 131072

__device__ __forceinline__ float sigf(float x) { return 1.0f / (1.0f + __expf(-x)); }
__device__ __forceinline__ float tanhf_(float x) {
  float e = __expf(-2.0f * fabsf(x));
  float y = (1.0f - e) / (1.0f + e);
  return copysignf(y, x);
}
__device__ __forceinline__ float4 ld4(const float* p) { return *reinterpret_cast<const float4*>(p); }
__device__ __forceinline__ void st4(float* p, float4 v) { *reinterpret_cast<float4*>(p) = v; }

// ---------------------------------------------------------------------------
// k_pre (one launch, 3 independent block families):
//  [0,604):    Wcs[co][d] = sum_c wc[co][c*512+d]           (46.7 MB stream)
//  [604,1372): U_z = (z<2 ? w3u : 0) - fac*Wsum_z  (fold hu3 + fac into weights)
//              Wsum_z[j,k] = w_zw[j,k] + w_zw[j,512+k]
//  [1372,1404): Xps[p][k] = colsum partial of X rows 8p..8p+8 (S seed, iter 1)
// ---------------------------------------------------------------------------
__global__ void __launch_bounds__(256) k_pre(
    const float* __restrict__ mat, const float* __restrict__ w3w,
    const float* __restrict__ w4w, const float* __restrict__ w5w,
    const float* __restrict__ w3u, const float* __restrict__ X,
    const float* __restrict__ wc, float* __restrict__ U,
    float* __restrict__ Wcs, float* __restrict__ Hps) {
  __shared__ float4 red4[256];
  const int t = threadIdx.x;
  const int bx = blockIdx.x;
  if (bx < 604) {  // ---- Wcs ----
    const int co = bx >> 2, q = bx & 3;
    const int d = q * 128 + (t & 31) * 4;
    const int g = t >> 5;
    const float* row = wc + (size_t)co * (CNUM * DDIM);
    float4 s = make_float4(0.f, 0.f, 0.f, 0.f);
    for (int c = g; c < CNUM; c += 8) {
      const float4 v = ld4(row + c * DDIM + d);
      s.x += v.x; s.y += v.y; s.z += v.z; s.w += v.w;
    }
    red4[t] = s;
    __syncthreads();
    if (t < 128) { red4[t].x += red4[t+128].x; red4[t].y += red4[t+128].y;
                   red4[t].z += red4[t+128].z; red4[t].w += red4[t+128].w; }
    __syncthreads();
    if (t < 64)  { red4[t].x += red4[t+64].x; red4[t].y += red4[t+64].y;
                   red4[t].z += red4[t+64].z; red4[t].w += red4[t+64].w; }
    __syncthreads();
    if (t < 32) {
      float4 o = red4[t];
      o.x += red4[t+32].x; o.y += red4[t+32].y; o.z += red4[t+32].z; o.w += red4[t+32].w;
      st4(Wcs + co * DDIM + q * 128 + t * 4, o);
    }
    return;
  }
  if (bx < 1372) {  // ---- U ----
    const float fac = mat[0] * (float)CNUM;
    const int gid = (bx - 604) * 256 + t;  // float4 unit, [0, 196608)
    const int z = gid >> 16;
    const int r = gid & 65535;
    const int j = r >> 7, k4 = (r & 127) * 4;
    const float* wz = (z == 0) ? w3w : (z == 1) ? w4w : w5w;
    const float4 a = ld4(wz + (size_t)j * 1024 + k4);
    const float4 b = ld4(wz + (size_t)j * 1024 + 512 + k4);
    float4 u = make_float4(-fac * (a.x + b.x), -fac * (a.y + b.y),
                           -fac * (a.z + b.z), -fac * (a.w + b.w));
    if (z < 2) {
      const float4 w3 = ld4(w3u + (size_t)j * DDIM + k4);
      u.x += w3.x; u.y += w3.y; u.z += w3.z; u.w += w3.w;
    }
    st4(U + (size_t)z * (DDIM * DDIM) + (size_t)j * DDIM + k4, u);
    return;
  }
  {  // ---- Xps ----
    const int p = bx - 1372;
    const int m0 = p * 8;
    const int k2 = t * 2;
    float s0 = 0.f, s1 = 0.f;
#pragma unroll
    for (int r = 0; r < 8; ++r) {
      const float2 v = *reinterpret_cast<const float2*>(X + (m0 + r) * DDIM + k2);
      s0 += v.x; s1 += v.y;
    }
    Hps[p * DDIM + k2] = s0;
    Hps[p * DDIM + k2 + 1] = s1;
  }
}

// ---------------------------------------------------------------------------
// k_G1: P_z[kh] partials of H*U_z^T (z=0,1,2). Tile 16m x 64j x 256k.
// grid 24 vec-blocks + 768 GEMM (3z x 8jb x 2kh x 16mb, XCD-pinned).
// vec blocks: S[k] = sum_p Hps[p][k]; vec_z[j] = fac*(S·Wsum_z^T)[j] + biases.
// LDS: sA[k][16m] XOR-swizzled (b128 wave-uniform reads), sB stride-66.
// ---------------------------------------------------------------------------
__global__ void __launch_bounds__(256) k_G1(
    const float* __restrict__ Hc, const float* __restrict__ U,
    const float* __restrict__ Hps, const float* __restrict__ w3w,
    const float* __restrict__ w4w, const float* __restrict__ w5w,
    const float* __restrict__ b3w, const float* __restrict__ b3u,
    const float* __restrict__ b4w, const float* __restrict__ b5w,
    const float* __restrict__ b5u, const float* __restrict__ mat,
    float* __restrict__ P, float* __restrict__ vec) {
  __shared__ float sA[64 * 16];
  __shared__ float sB[64 * 66];
  const int t = threadIdx.x;
  const int bx = blockIdx.x;
  if (bx < 24) {  // ---- vec tail: S build + matvec ----
    const float fac = mat[0] * (float)CNUM;
    const int z = bx >> 3, jp = bx & 7, j0 = jp * 64;
    float* S = sA;  // 512 floats
    {
      const int k2 = t * 2;
      float s0 = 0.f, s1 = 0.f;
#pragma unroll
      for (int p = 0; p < 32; ++p) {
        const float2 v = *reinterpret_cast<const float2*>(Hps + p * DDIM + k2);
        s0 += v.x; s1 += v.y;
      }
      S[k2] = s0; S[k2 + 1] = s1;
    }
    __syncthreads();
    const int jl = t >> 2, q = t & 3;
    const int row = j0 + jl;
    const float* wz = (z == 0) ? w3w : (z == 1) ? w4w : w5w;
    const float* base = wz + (size_t)row * 1024 + q * 128;
    float sum = 0.f;
#pragma unroll
    for (int i = 0; i < 32; ++i) {
      const float4 f1 = ld4(base + 4 * i);
      const float4 f2 = ld4(base + 512 + 4 * i);
      const float4 s4 = ld4(S + q * 128 + 4 * i);
      sum = fmaf(f1.x + f2.x, s4.x, sum);
      sum = fmaf(f1.y + f2.y, s4.y, sum);
      sum = fmaf(f1.z + f2.z, s4.z, sum);
      sum = fmaf(f1.w + f2.w, s4.w, sum);
    }
    sum += __shfl_xor(sum, 1, 64);
    sum += __shfl_xor(sum, 2, 64);
    if (q == 0) {
      const float bias = (z == 0) ? (b3w[row] + b3u[row])
                       : (z == 1) ? (b4w[row] + b3u[row])
                                  : (b5w[row] + b5u[row]);
      vec[z * DDIM + row] = fac * sum + bias;
    }
    return;
  }
  // ---- GEMM path ----
  const int bg = bx - 24;
  const int xcd = bg & 7, slot = bg >> 3;          // slot 0..95
  const int pp = xcd * 6 + (slot >> 4);            // 48 panels
  const int mb = slot & 15;
  const int z = pp >> 4, rr = pp & 15;
  const int jb = rr >> 1, kh = rr & 1;
  const int m0 = mb * 16, j0 = jb * 64, kb = kh * 256;
  const float* Bp = U + (size_t)z * (DDIM * DDIM);
  const int lane = t & 63, wv = t >> 6;
  const int m = t >> 4, k4 = (t & 15) * 4;
  const int jr = t >> 2, kf = (t & 3) * 4;
  float4 rav, rbv[4];
  float acc[4] = {0.f, 0.f, 0.f, 0.f};

#define G1_LOAD(c)                                                          \
  {                                                                         \
    rav = ld4(Hc + (size_t)(m0 + m) * DDIM + kb + (c) * 64 + k4);           \
    const float* bp = Bp + (size_t)(j0 + jr) * DDIM + kb + (c) * 64 + kf;   \
    rbv[0] = ld4(bp);      rbv[1] = ld4(bp + 16);                           \
    rbv[2] = ld4(bp + 32); rbv[3] = ld4(bp + 48);                           \
  }

  G1_LOAD(0);
  for (int c = 0; c < 4; ++c) {
    __syncthreads();
    {
      float* da = sA + k4 * 16 + (m ^ ((t & 3) << 2));
      da[0] = rav.x; da[16] = rav.y; da[32] = rav.z; da[48] = rav.w;
      float* db = sB + kf * 66 + jr;
#pragma unroll
      for (int i = 0; i < 4; ++i) {
        db[(i * 16 + 0) * 66] = rbv[i].x;
        db[(i * 16 + 1) * 66] = rbv[i].y;
        db[(i * 16 + 2) * 66] = rbv[i].z;
        db[(i * 16 + 3) * 66] = rbv[i].w;
      }
    }
    __syncthreads();
    if (c < 3) G1_LOAD(c + 1);
    for (int k4o = 0; k4o < 16; ++k4o) {
      const int abase = (k4o * 4) * 16 + ((wv ^ (k4o & 3)) << 2);
#pragma unroll
      for (int u = 0; u < 4; ++u) {
        const int kk = k4o * 4 + u;
        const float b = sB[kk * 66 + lane];
        const float4 a = ld4(sA + abase + u * 16);
        acc[0] = fmaf(a.x, b, acc[0]); acc[1] = fmaf(a.y, b, acc[1]);
        acc[2] = fmaf(a.z, b, acc[2]); acc[3] = fmaf(a.w, b, acc[3]);
      }
    }
  }
#undef G1_LOAD
  float* op = P + (size_t)(z * 2 + kh) * NBDD;
#pragma unroll
  for (int i = 0; i < 4; ++i)
    op[(size_t)(m0 + wv * 4 + i) * DDIM + j0 + lane] = acc[i];
}

// ---------------------------------------------------------------------------
// k_G2u: rv = sig(P1a+P1b+vec1[k]); acc = (rv.H)*w5u^T (full K resident);
// epilogue = full GRU update (zv/hv from P0/P2 + vec) -> Hn, plus Hn column
// partials -> Hps (next iteration's S). Tile 8m x 32j, grid (32mb x 16jb)=512.
// ---------------------------------------------------------------------------
__global__ void __launch_bounds__(256) k_G2u(
    const float* __restrict__ Hc, const float* __restrict__ P,
    const float* __restrict__ vec, const float* __restrict__ w5u,
    float* __restrict__ Hn, float* __restrict__ Hps) {
  __shared__ float sA[8 * 516];   // rv*H, [m][k] padded
  __shared__ float sB[32 * 68];   // w5u chunk, [j][k] padded
  __shared__ float sv1[DDIM];
  __shared__ float sv0[32], sv2[32];
  __shared__ float sred[4 * 32];
  const int t = threadIdx.x;
  const int mb = blockIdx.x >> 4, jb = blockIdx.x & 15;
  const int m0 = mb * 8, j0 = jb * 32;
  {  // stage vec slices
    const float2 v = *reinterpret_cast<const float2*>(vec + DDIM + t * 2);
    sv1[t * 2] = v.x; sv1[t * 2 + 1] = v.y;
    if (t < 32) { sv0[t] = vec[j0 + t]; sv2[t] = vec[2 * DDIM + j0 + t]; }
  }
  __syncthreads();
  {  // A-prep: rv ⊙ H for 8 rows x 512 k
    const int m = t >> 5, kq = (t & 31) * 4;
#pragma unroll
    for (int i = 0; i < 4; ++i) {
      const int k = kq + i * 128;
      const int idx = (m0 + m) * DDIM + k;
      const float4 p1a = ld4(P + 2 * (size_t)NBDD + idx);
      const float4 p1b = ld4(P + 3 * (size_t)NBDD + idx);
      const float4 v1 = ld4(sv1 + k);
      const float4 hh = ld4(Hc + idx);
      st4(sA + m * 516 + k,
          make_float4(sigf(p1a.x + p1b.x + v1.x) * hh.x,
                      sigf(p1a.y + p1b.y + v1.y) * hh.y,
                      sigf(p1a.z + p1b.z + v1.z) * hh.z,
                      sigf(p1a.w + p1b.w + v1.w) * hh.w));
    }
  }
  const int jr = t >> 3, kf = (t & 7) * 8;
  const int j = t & 31, m = t >> 5;
  float4 rb0, rb1;
  float acc = 0.f;
#define G2_LOADB(c)                                                    \
  {                                                                    \
    const float* bp = w5u + (size_t)(j0 + jr) * DDIM + (c) * 64 + kf;  \
    rb0 = ld4(bp); rb1 = ld4(bp + 4);                                  \
  }
  G2_LOADB(0);
  for (int c = 0; c < 8; ++c) {
    __syncthreads();  // sA ready (c==0) / prev chunk consumed
    st4(sB + jr * 68 + kf, rb0);
    st4(sB + jr * 68 + kf + 4, rb1);
    __syncthreads();
    if (c < 7) G2_LOADB(c + 1);
#pragma unroll
    for (int k4o = 0; k4o < 16; ++k4o) {
      const float4 a = ld4(sA + m * 516 + c * 64 + k4o * 4);
      const float4 b = ld4(sB + j * 68 + k4o * 4);
      acc = fmaf(a.x, b.x, acc); acc = fmaf(a.y, b.y, acc);
      acc = fmaf(a.z, b.z, acc); acc = fmaf(a.w, b.w, acc);
    }
  }
#undef G2_LOADB
  // epilogue: GRU update
  const int idx = (m0 + m) * DDIM + j0 + j;
  const float zv = sigf(P[idx] + P[(size_t)NBDD + idx] + sv0[j]);
  const float hv = tanhf_(P[4 * (size_t)NBDD + idx] + P[5 * (size_t)NBDD + idx] +
                          sv2[j] + acc);
  const float hn = (1.f - zv) * Hc[idx] + zv * hv;
  Hn[idx] = hn;
  // column partials of Hn over this block's 8 rows (deterministic)
  const float pr = hn + __shfl_xor(hn, 32, 64);
  const int lane = t & 63, wv = t >> 6;
  if (lane < 32) sred[wv * 32 + lane] = pr;
  __syncthreads();
  if (t < 32)
    Hps[mb * DDIM + j0 + t] =
        sred[t] + sred[32 + t] + sred[64 + t] + sred[96 + t];
}

// ---------------------------------------------------------------------------
// k_out (split-K=4 at the [H|X] concat + halves): Po[p] partials of
// [H|X]*wo^T. Tile 16m x 64j x 256k; grid 512 = 8jb x 4p x 16mb; XCD pinned.
// ---------------------------------------------------------------------------
__global__ void __launch_bounds__(256) k_out(const float* __restrict__ H,
                                             const float* __restrict__ X,
                                             const float* __restrict__ wo,
                                             float* __restrict__ Po) {
  __shared__ float sA[64 * 16];
  __shared__ float sB[64 * 66];
  const int t = threadIdx.x;
  const int bx = blockIdx.x;
  const int xcd = bx & 7, slot = bx >> 3;
  const int pp = xcd * 4 + (slot >> 4);
  const int mb = slot & 15;
  const int jb = pp >> 2, p = pp & 3;
  const int s = p >> 1, ksh = p & 1;
  const int m0 = mb * 16, j0 = jb * 64, kb = ksh * 256;
  const float* A = s ? X : H;
  const int lane = t & 63, wv = t >> 6;
  const int m = t >> 4, k4 = (t & 15) * 4;
  const int jr = t >> 2, kf = (t & 3) * 4;
  float4 rav, rbv[4];
  float acc[4] = {0.f, 0.f, 0.f, 0.f};

#define KO_LOAD(c)                                                              \
  {                                                                             \
    rav = ld4(A + (size_t)(m0 + m) * DDIM + kb + (c) * 64 + k4);                \
    const float* bp = wo + (size_t)(j0 + jr) * 1024 + s * 512 + kb + (c) * 64 + kf; \
    rbv[0] = ld4(bp);      rbv[1] = ld4(bp + 16);                               \
    rbv[2] = ld4(bp + 32); rbv[3] = ld4(bp + 48);                               \
  }

  KO_LOAD(0);
  for (int c = 0; c < 4; ++c) {
    __syncthreads();
    {
      float* da = sA + k4 * 16 + (m ^ ((t & 3) << 2));
      da[0] = rav.x; da[16] = rav.y; da[32] = rav.z; da[48] = rav.w;
      float* db = sB + kf * 66 + jr;
#pragma unroll
      for (int i = 0; i < 4; ++i) {
        db[(i * 16 + 0) * 66] = rbv[i].x;
        db[(i * 16 + 1) * 66] = rbv[i].y;
        db[(i * 16 + 2) * 66] = rbv[i].z;
        db[(i * 16 + 3) * 66] = rbv[i].w;
      }
    }
    __syncthreads();
    if (c < 3) KO_LOAD(c + 1);
    for (int k4o = 0; k4o < 16; ++k4o) {
      const int abase = (k4o * 4) * 16 + ((wv ^ (k4o & 3)) << 2);
#pragma unroll
      for (int u = 0; u < 4; ++u) {
        const int kk = k4o * 4 + u;
        const float b = sB[kk * 66 + lane];
        const float4 a = ld4(sA + abase + u * 16);
        acc[0] = fmaf(a.x, b, acc[0]); acc[1] = fmaf(a.y, b, acc[1]);
        acc[2] = fmaf(a.z, b, acc[2]); acc[3] = fmaf(a.w, b, acc[3]);
      }
    }
  }
#undef KO_LOAD
#pragma unroll
  for (int i = 0; i < 4; ++i)
    Po[(size_t)p * NBDD + (size_t)(m0 + wv * 4 + i) * DDIM + j0 + lane] = acc[i];
}

// ---------------------------------------------------------------------------
// k_obj: out = relu(sum Po + bo) * Wcs^T + bc. Tile 8m x 64j, grid (32,3).
// ---------------------------------------------------------------------------
__global__ void __launch_bounds__(256) k_obj(const float* __restrict__ Po,
                                             const float* __restrict__ bo,
                                             const float* __restrict__ Wcs,
                                             const float* __restrict__ bc,
                                             float* __restrict__ out) {
  __shared__ float sAo[8 * 519];
  __shared__ float sB[64 * 66];
  const int t = threadIdx.x;
  const int m0 = blockIdx.x * 8, j0 = blockIdx.y * 64;
  const int lane = t & 63, wv = t >> 6;
  const int jr = t >> 2, kf = (t & 3) * 4;
  const int co = j0 + jr;
  {
    const int m = t >> 5, ks4 = (t & 31) * 4;
#pragma unroll
    for (int kb2 = 0; kb2 < 4; ++kb2) {
      const int k = kb2 * 128 + ks4;
      const int idx = (m0 + m) * DDIM + k;
      const float4 p0 = ld4(Po + idx);
      const float4 p1 = ld4(Po + (size_t)NBDD + idx);
      const float4 p2 = ld4(Po + (size_t)2 * NBDD + idx);
      const float4 p3 = ld4(Po + (size_t)3 * NBDD + idx);
      const float4 bb = ld4(bo + k);
      float* da = sAo + m * 519 + k;
      da[0] = fmaxf(p0.x + p1.x + p2.x + p3.x + bb.x, 0.f);
      da[1] = fmaxf(p0.y + p1.y + p2.y + p3.y + bb.y, 0.f);
      da[2] = fmaxf(p0.z + p1.z + p2.z + p3.z + bb.z, 0.f);
      da[3] = fmaxf(p0.w + p1.w + p2.w + p3.w + bb.w, 0.f);
    }
  }
  float4 rbv[4];
  float acc[2] = {0.f, 0.f};
#define OB_LOADB(c)                                                         \
  {                                                                         \
    if (co < CNUM) {                                                        \
      const float* bp = Wcs + (size_t)co * DDIM + (c) * 64 + kf;            \
      rbv[0] = ld4(bp);      rbv[1] = ld4(bp + 16);                         \
      rbv[2] = ld4(bp + 32); rbv[3] = ld4(bp + 48);                         \
    } else {                                                                \
      rbv[0] = rbv[1] = rbv[2] = rbv[3] = make_float4(0.f, 0.f, 0.f, 0.f);  \
    }                                                                       \
  }
  OB_LOADB(0);
  for (int c = 0; c < 8; ++c) {
    __syncthreads();
    {
      float* db = sB + kf * 66 + jr;
#pragma unroll
      for (int i = 0; i < 4; ++i) {
        db[(i * 16 + 0) * 66] = rbv[i].x;
        db[(i * 16 + 1) * 66] = rbv[i].y;
        db[(i * 16 + 2) * 66] = rbv[i].z;
        db[(i * 16 + 3) * 66] = rbv[i].w;
      }
    }
    __syncthreads();
    if (c < 7) OB_LOADB(c + 1);
    const float* a0p = sAo + (wv * 2) * 519 + c * 64;
    const float* a1p = a0p + 519;
#pragma unroll 16
    for (int kk = 0; kk < 64; ++kk) {
      const float b = sB[kk * 66 + lane];
      acc[0] = fmaf(a0p[kk], b, acc[0]);
      acc[1] = fmaf(a1p[kk], b, acc[1]);
    }
  }
#undef OB_LOADB
  const int c_ = j0 + lane;
  if (c_ < CNUM) {
    const float bcv = bc[c_];
    out[(m0 + wv * 2 + 0) * CNUM + c_] = acc[0] + bcv;
    out[(m0 + wv * 2 + 1) * CNUM + c_] = acc[1] + bcv;
  }
}

extern "C" void kernel_launch(void* const* d_in, const int* in_sizes, int n_in,
                              void* d_out, int out_size, void* d_ws, size_t ws_size,
                              hipStream_t stream) {
  const float* X = (const float*)d_in[0];
  const float* mat = (const float*)d_in[1];
  const float* w3w = (const float*)d_in[2];
  const float* b3w = (const float*)d_in[3];
  const float* w3u = (const float*)d_in[4];
  const float* b3u = (const float*)d_in[5];
  const float* w4w = (const float*)d_in[6];
  const float* b4w = (const float*)d_in[7];
  // d_in[8], d_in[9] (w4u, b4u) unused — reference reuses w3u/b3u (faithful bug)
  const float* w5w = (const float*)d_in[10];
  const float* b5w = (const float*)d_in[11];
  const float* w5u = (const float*)d_in[12];
  const float* b5u = (const float*)d_in[13];
  const float* wo = (const float*)d_in[14];
  const float* bo = (const float*)d_in[15];
  const float* wc = (const float*)d_in[16];
  const float* bc = (const float*)d_in[17];
  float* out = (float*)d_out;
  float* ws = (float*)d_ws;

  // workspace (floats): ~9.9 MB
  float* U = ws;                  // 3*512*512 = 786432
  float* Wcs = U + 786432;        // 151*512   = 77312
  float* Hps = Wcs + 77312;       // 32*512    = 16384
  float* vec = Hps + 16384;       // 3*512     = 1536
  float* P = vec + 1536;          // 6*131072  = 786432
  float* H0 = P + 786432;         // 131072
  float* H1 = H0 + 131072;        // 131072
  float* Po = H1 + 131072;        // 4*131072  = 524288

  k_pre<<<1404, 256, 0, stream>>>(mat, w3w, w4w, w5w, w3u, X, wc, U, Wcs, Hps);

  // iter 1 (Hc = X)
  k_G1<<<792, 256, 0, stream>>>(X, U, Hps, w3w, w4w, w5w, b3w, b3u, b4w, b5w, b5u, mat, P, vec);
  k_G2u<<<512, 256, 0, stream>>>(X, P, vec, w5u, H0, Hps);
  // iter 2
  k_G1<<<792, 256, 0, stream>>>(H0, U, Hps, w3w, w4w, w5w, b3w, b3u, b4w, b5w, b5u, mat, P, vec);
  k_G2u<<<512, 256, 0, stream>>>(H0, P, vec, w5u, H1, Hps);
  // iter 3
  k_G1<<<792, 256, 0, stream>>>(H1, U, Hps, w3w, w4w, w5w, b3w, b3u, b4w, b5w, b5u, mat, P, vec);
  k_G2u<<<512, 256, 0, stream>>>(H1, P, vec, w5u, H0, Hps);
  // epilogue
  k_out<<<512, 256, 0, stream>>>(H0, X, wo, Po);
  k_obj<<<dim3(32, 3), 256, 0, stream>>>(Po, bo, Wcs, bc, out);
}